// Round 5
// baseline (5128.584 us; speedup 1.0000x reference)
//
#include <hip/hip_runtime.h>
#include <hip/hip_bf16.h>
#include <stdint.h>

typedef unsigned short u16;
typedef __bf16 bf16x8 __attribute__((ext_vector_type(8)));
typedef float f32x4 __attribute__((ext_vector_type(4)));

// ---------- helpers ----------
__device__ __forceinline__ u16 f2bf(float f) {
  uint32_t u = __float_as_uint(f);
  u = (u + 0x7FFFu + ((u >> 16) & 1u)) >> 16;  // RNE
  return (u16)u;
}
__device__ __forceinline__ float bf2f(u16 x) {
  return __uint_as_float(((uint32_t)x) << 16);
}
__device__ __forceinline__ float blo(uint32_t w) { return __uint_as_float(w << 16); }
__device__ __forceinline__ float bhi(uint32_t w) { return __uint_as_float(w & 0xFFFF0000u); }

__device__ __forceinline__ void gl2lds16(const void* g, void* l) {
  __builtin_amdgcn_global_load_lds(
      (const __attribute__((address_space(1))) void*)g,
      (__attribute__((address_space(3))) void*)l, 16, 0, 0);
}

// ---------- f32 -> bf16 array convert (n4 = count/4, exact) ----------
__global__ void cvt_bf16_arr(const float* __restrict__ in, u16* __restrict__ out, int n4) {
  int i = blockIdx.x * blockDim.x + threadIdx.x;
  if (i >= n4) return;
  float4 v = ((const float4*)in)[i];
  ushort4 o;
  o.x = f2bf(v.x); o.y = f2bf(v.y); o.z = f2bf(v.z); o.w = f2bf(v.w);
  ((ushort4*)out)[i] = o;
}

// ---------- pack Whh[j][k] -> u32 {bf16(k),bf16(k+1)} at [k/2][j] ----------
__global__ void pack_whh(const float* __restrict__ W, uint32_t* __restrict__ out) {
  int idx = blockIdx.x * 256 + threadIdx.x;   // 512 blocks * 256 thr
  int p = idx >> 9, j = idx & 511;
  float a = W[j * 512 + 2 * p];
  float b = W[j * 512 + 2 * p + 1];
  out[p * 512 + j] = (uint32_t)f2bf(a) | ((uint32_t)f2bf(b) << 16);
}

// ---------- gather token embeddings -> bf16 rows (B-major, 128 per batch) ----------
__global__ void gather_embed(const int* __restrict__ tok, const float* __restrict__ embed,
                             u16* __restrict__ out, int tokStride) {
  int m = blockIdx.x;          // 0..4095 : b*128 + pos
  int t = threadIdx.x;         // 128 threads, 4 floats each
  int token = tok[(m >> 7) * tokStride + (m & 127)];
  float4 v = ((const float4*)(embed + (long)token * 512))[t];
  ushort4 o;
  o.x = f2bf(v.x); o.y = f2bf(v.y); o.z = f2bf(v.z); o.w = f2bf(v.w);
  ((ushort4*)(out + (long)m * 512))[t] = o;
}

// ---------- bf16 MFMA GEMM: C[M,N] = A[M,K] * B[N,K]^T (+bias[n]) ----------
// (round-1 verbatim; 128x128 tile, BK=32, 4 waves, 16x16x32 MFMA)
__global__ __launch_bounds__(256) void gemm_bf16_kernel(
    const u16* __restrict__ A, const u16* __restrict__ B,
    const float* __restrict__ bias, float* __restrict__ C,
    int M, int N, int K) {
  __shared__ __align__(16) u16 As[4096];
  __shared__ __align__(16) u16 Bs[4096];
  const int tid = threadIdx.x;
  const int lane = tid & 63;
  const int wv = tid >> 6;
  const int wr = wv >> 1, wc = wv & 1;
  const long m0 = (long)blockIdx.y * 128;
  const long n0 = (long)blockIdx.x * 128;

  f32x4 zero = {0.f, 0.f, 0.f, 0.f};
  f32x4 acc[4][4];
#pragma unroll
  for (int i = 0; i < 4; ++i)
#pragma unroll
    for (int j = 0; j < 4; ++j) acc[i][j] = zero;

  const u16* Ag = A + (m0 + (tid >> 2)) * (long)K + (tid & 3) * 8;
  const u16* Bg = B + (n0 + (tid >> 2)) * (long)K + (tid & 3) * 8;
  const u16* Ag2 = Ag + 64 * (long)K;
  const u16* Bg2 = Bg + 64 * (long)K;
  u16* AsW = As + (tid >> 6) * 512;   // wave-uniform LDS base
  u16* BsW = Bs + (tid >> 6) * 512;
  const int ra = (wr * 64 + (lane & 15)) * 32 + (lane >> 4) * 8;
  const int rb = (wc * 64 + (lane & 15)) * 32 + (lane >> 4) * 8;

  for (int kt = 0; kt < K; kt += 32) {
    __syncthreads();                         // previous-tile reads done
    gl2lds16(Ag + kt, AsW);                  // rows 0..63
    gl2lds16(Ag2 + kt, AsW + 2048);          // rows 64..127
    gl2lds16(Bg + kt, BsW);
    gl2lds16(Bg2 + kt, BsW + 2048);
    __syncthreads();                         // barrier drains vmcnt
    bf16x8 af[4], bfr[4];
#pragma unroll
    for (int i = 0; i < 4; ++i) af[i] = *(const bf16x8*)&As[ra + i * 512];
#pragma unroll
    for (int j = 0; j < 4; ++j) bfr[j] = *(const bf16x8*)&Bs[rb + j * 512];
#pragma unroll
    for (int i = 0; i < 4; ++i)
#pragma unroll
      for (int j = 0; j < 4; ++j)
        acc[i][j] = __builtin_amdgcn_mfma_f32_16x16x32_bf16(af[i], bfr[j], acc[i][j], 0, 0, 0);
  }

#pragma unroll
  for (int i = 0; i < 4; ++i) {
    const long row = m0 + wr * 64 + i * 16 + ((lane >> 4) << 2);
#pragma unroll
    for (int j = 0; j < 4; ++j) {
      const long col = n0 + wc * 64 + j * 16 + (lane & 15);
      const float bv = bias ? bias[col] : 0.f;
#pragma unroll
      for (int r = 0; r < 4; ++r)
        C[(row + r) * (long)N + col] = acc[i][j][r] + bv;
    }
  }
}

// ---------- RNN recurrence v2: fits the 128-VGPR budget ----------
// 1 block per batch, 1024 threads. Thread (j = t>>1, half = t&1) owns HALF of
// Whh row j: 128 bf16-pairs covering k in [half*256, half*256+256).
//   - pairs 0..95   : 24 named uint4 in VGPRs (96 regs)
//   - pairs 96..127 : LDS uint4[8][1024] (128 KB, coalesced ds_read_b128)
// h kept f32 in LDS (broadcast reads). Halves combined via __shfl_xor(a,1)
// (lanes 2j / 2j+1 are adjacent in the same wave). Numerics = round-3 path.

#define FOR24(M) \
  M(0) M(1) M(2) M(3) M(4) M(5) M(6) M(7) M(8) M(9) M(10) M(11) \
  M(12) M(13) M(14) M(15) M(16) M(17) M(18) M(19) M(20) M(21) M(22) M(23)

__global__ __launch_bounds__(1024, 4) void rnn_core(
    const float* __restrict__ pre,            // [B*128][512] f32
    const uint32_t* __restrict__ WhhP,        // [256][512] bf16-pairs [p][j]
    const float* __restrict__ bih, const float* __restrict__ bhh,
    const float* __restrict__ h0,             // [B][512] f32 or null (zeros)
    float* __restrict__ hOutF, long ldF,      // f32 h out (or null)
    u16* __restrict__ hOutB, long ldB_,       // bf16 h out
    float* __restrict__ hLast)                // [B][512] f32 or null
{
  const int b = blockIdx.x, t = threadIdx.x;
  const int j = t >> 1, half = t & 1;
  __shared__ __align__(16) float h_sh[512];
  __shared__ __align__(16) uint4 wlds4[8][1024];   // pairs 96..127 per thread
  const uint32_t* Wp = WhhP + (long)half * 128 * 512 + j;  // global pair base
  // 96 pairs in 24 named uint4 registers
#define LDW_(i) uint4 wr##i; \
  wr##i.x = Wp[(long)(4*(i)+0) * 512]; wr##i.y = Wp[(long)(4*(i)+1) * 512]; \
  wr##i.z = Wp[(long)(4*(i)+2) * 512]; wr##i.w = Wp[(long)(4*(i)+3) * 512];
  FOR24(LDW_)
#undef LDW_
  // 32 pairs into LDS as 8 uint4 groups
#pragma unroll
  for (int G = 0; G < 8; ++G) {
    uint4 w;
    w.x = Wp[(long)(96 + 4*G + 0) * 512]; w.y = Wp[(long)(96 + 4*G + 1) * 512];
    w.z = Wp[(long)(96 + 4*G + 2) * 512]; w.w = Wp[(long)(96 + 4*G + 3) * 512];
    wlds4[G][t] = w;
  }
  const float biasj = bih[j] + bhh[j];
  if (!half) h_sh[j] = h0 ? h0[(long)b * 512 + j] : 0.f;
  const float* preB = pre + (long)b * 128 * 512 + j;
  const int hq = half * 64;                 // float4 base into h for this half
  __syncthreads();

  for (int st = 0; st < 128; ++st) {
    const float4* H4 = (const float4*)h_sh;
    float a0 = 0.f, a1 = 0.f, a2 = 0.f, a3 = 0.f;
    // pairs 0..95 from named VGPRs
#define ACC_(g) { \
    float4 ha = H4[hq + 2*(g)]; \
    float4 hb = H4[hq + 2*(g) + 1]; \
    a0 += ha.x * blo(wr##g.x) + ha.y * bhi(wr##g.x); \
    a1 += ha.z * blo(wr##g.y) + ha.w * bhi(wr##g.y); \
    a2 += hb.x * blo(wr##g.z) + hb.y * bhi(wr##g.z); \
    a3 += hb.z * blo(wr##g.w) + hb.w * bhi(wr##g.w); }
    FOR24(ACC_)
#undef ACC_
    // pairs 96..127 from LDS
#pragma unroll
    for (int G = 0; G < 8; ++G) {
      uint4 w = wlds4[G][t];
      float4 ha = H4[hq + 48 + 2*G];
      float4 hb = H4[hq + 48 + 2*G + 1];
      a0 += ha.x * blo(w.x) + ha.y * bhi(w.x);
      a1 += ha.z * blo(w.y) + ha.w * bhi(w.y);
      a2 += hb.x * blo(w.z) + hb.y * bhi(w.z);
      a3 += hb.z * blo(w.w) + hb.w * bhi(w.w);
    }
    float a = (a0 + a1) + (a2 + a3);
    a += __shfl_xor(a, 1, 64);              // combine the two k-halves
    float h = tanhf(preB[(long)st * 512] + biasj + a);
    __syncthreads();                        // all h_sh reads done
    if (!half) {
      h_sh[j] = h;
      if (hOutF) hOutF[((long)b * 128 + st) * ldF + j] = h;
      hOutB[((long)b * 128 + st) * ldB_ + j] = f2bf(h);
      if (hLast && st == 127) hLast[(long)b * 512 + j] = h;
    }
    __syncthreads();                        // new h visible
  }
}

// ---------- fused attention: scores -> softmax -> att out -> ctx (all f32) ----------
// grid (32 b, 8 t-groups), block 1024 (16 waves, wave w owns t = y*16+w)
__global__ __launch_bounds__(1024) void attn_fused(
    const u16* __restrict__ hcat,        // bf16, dec_h in cols 0..511
    const float* __restrict__ encT,      // [B][128 s][512] f32
    const float* __restrict__ encBsh,    // [B][128 s][512] f32
    u16* __restrict__ hcatW,             // write ctx into cols 512..1023 (bf16)
    float* __restrict__ attOut)          // [B][128 s][128 t] f32
{
  const int b = blockIdx.x;
  const int w = threadIdx.x >> 6, lane = threadIdx.x & 63;
  const int t = blockIdx.y * 16 + w;
  __shared__ float at[16][128];

  // dec_h row t -> registers (bf16 -> f32)
  float hreg[8];
  const u16* hrow = hcat + ((long)b * 128 + t) * 1024;
#pragma unroll
  for (int i = 0; i < 8; ++i) hreg[i] = bf2f(hrow[lane + i * 64]);

  // scores: score[s] = dec_h[t] . enc_t[s]
  const float* et = encT + (long)b * 128 * 512;
  for (int s = 0; s < 128; ++s) {
    const float* row = et + (long)s * 512;
    float a = 0.f;
#pragma unroll
    for (int i = 0; i < 8; ++i) a += hreg[i] * row[lane + i * 64];
#pragma unroll
    for (int o = 32; o; o >>= 1) a += __shfl_xor(a, o, 64);
    if (lane == 0) at[w][s] = a;
  }
  __syncthreads();

  // softmax over s (per wave, 2 values per lane)
  float s0 = at[w][lane], s1 = at[w][lane + 64];
  float mx = fmaxf(s0, s1);
#pragma unroll
  for (int o = 32; o; o >>= 1) mx = fmaxf(mx, __shfl_xor(mx, o, 64));
  float e0 = __expf(s0 - mx), e1 = __expf(s1 - mx);
  float sm = e0 + e1;
#pragma unroll
  for (int o = 32; o; o >>= 1) sm += __shfl_xor(sm, o, 64);
  float inv = 1.f / sm;
  e0 *= inv; e1 *= inv;
  at[w][lane] = e0;
  at[w][lane + 64] = e1;
  __syncthreads();

  // att output: att[b][s][t]
  attOut[(long)b * 16384 + (long)lane * 128 + t] = e0;
  attOut[(long)b * 16384 + (long)(lane + 64) * 128 + t] = e1;

  // ctx[t][:] = sum_s attn[s] * enc_bsh[s][:]
  float acc[8] = {0.f, 0.f, 0.f, 0.f, 0.f, 0.f, 0.f, 0.f};
  const float* eb = encBsh + (long)b * 128 * 512;
  for (int s = 0; s < 128; ++s) {
    float ws = at[w][s];
    const float* row = eb + (long)s * 512;
#pragma unroll
    for (int i = 0; i < 8; ++i) acc[i] += ws * row[lane + i * 64];
  }
  u16* crow = hcatW + ((long)b * 128 + t) * 1024 + 512;
#pragma unroll
  for (int i = 0; i < 8; ++i) crow[lane + i * 64] = f2bf(acc[i]);
}

// ---------- launcher ----------
extern "C" void kernel_launch(void* const* d_in, const int* in_sizes, int n_in,
                              void* d_out, int out_size, void* d_ws, size_t ws_size,
                              hipStream_t stream) {
  (void)in_sizes; (void)n_in; (void)out_size; (void)ws_size;
  const int*   source = (const int*)d_in[0];
  const int*   target = (const int*)d_in[1];
  const float* embed  = (const float*)d_in[2];
  const float* encWih = (const float*)d_in[3];
  const float* encWhh = (const float*)d_in[4];
  const float* encBih = (const float*)d_in[5];
  const float* encBhh = (const float*)d_in[6];
  const float* decWih = (const float*)d_in[7];
  const float* decWhh = (const float*)d_in[8];
  const float* decBih = (const float*)d_in[9];
  const float* decBhh = (const float*)d_in[10];
  const float* attnW  = (const float*)d_in[11];
  const float* attnB  = (const float*)d_in[12];
  const float* outW   = (const float*)d_in[13];
  const float* outB   = (const float*)d_in[14];

  float* out_logits = (float*)d_out;
  float* out_att = out_logits + (long)32 * 128 * 32000;

  char* wsb = (char*)d_ws;
  size_t off = 0;
  auto alloc = [&](size_t bytes) {
    char* p = wsb + off;
    off += (bytes + 255) & ~(size_t)255;
    return p;
  };
  u16*      encA   = (u16*)alloc(4096l * 512 * 2);
  u16*      decA   = (u16*)alloc(4096l * 512 * 2);
  u16*      wihE   = (u16*)alloc(512l * 512 * 2);
  u16*      wihD   = (u16*)alloc(512l * 512 * 2);
  u16*      attnWb = (u16*)alloc(512l * 512 * 2);
  uint32_t* whhPe  = (uint32_t*)alloc(256l * 512 * 4);
  uint32_t* whhPd  = (uint32_t*)alloc(256l * 512 * 4);
  u16*      outWb  = (u16*)alloc(32000l * 1024 * 2);
  float*    preE   = (float*)alloc(4096l * 512 * 4);
  float*    preD   = (float*)alloc(4096l * 512 * 4);
  float*    encBsh = (float*)alloc(4096l * 512 * 4);
  u16*      encBf  = (u16*)alloc(4096l * 512 * 2);
  float*    encT   = (float*)alloc(4096l * 512 * 4);
  float*    hlast  = (float*)alloc(32l * 512 * 4);
  u16*      hcat   = (u16*)alloc(4096l * 1024 * 2);

  // weight conversions (independent)
  cvt_bf16_arr<<<256, 256, 0, stream>>>(encWih, wihE, 65536);
  cvt_bf16_arr<<<256, 256, 0, stream>>>(decWih, wihD, 65536);
  cvt_bf16_arr<<<256, 256, 0, stream>>>(attnW, attnWb, 65536);
  cvt_bf16_arr<<<32000, 256, 0, stream>>>(outW, outWb, 8192000);
  pack_whh<<<512, 256, 0, stream>>>(encWhh, whhPe);
  pack_whh<<<512, 256, 0, stream>>>(decWhh, whhPd);
  // embedding gathers
  gather_embed<<<4096, 128, 0, stream>>>(source, embed, encA, 128);
  gather_embed<<<4096, 128, 0, stream>>>(target, embed, decA, 129);
  // pre-activations for all timesteps: x @ Wih^T (f32 out)
  gemm_bf16_kernel<<<dim3(4, 32), 256, 0, stream>>>(encA, wihE, (const float*)nullptr, preE, 4096, 512, 512);
  gemm_bf16_kernel<<<dim3(4, 32), 256, 0, stream>>>(decA, wihD, (const float*)nullptr, preD, 4096, 512, 512);
  // encoder recurrence (h0=0): writes enc_bsh f32, encBf bf16, hlast f32
  rnn_core<<<32, 1024, 0, stream>>>(preE, whhPe, encBih, encBhh,
      (const float*)nullptr, encBsh, 512, encBf, 512, hlast);
  // enc_t = enc_h @ attn_W^T + attn_b (f32 out)
  gemm_bf16_kernel<<<dim3(4, 32), 256, 0, stream>>>(encBf, attnWb, attnB, encT, 4096, 512, 512);
  // decoder recurrence (h0 = enc last): writes dec_h bf16 into hcat left half
  rnn_core<<<32, 1024, 0, stream>>>(preD, whhPd, decBih, decBhh,
      hlast, (float*)nullptr, 512, hcat, 1024, (float*)nullptr);
  // fused attention: scores->softmax->att out->ctx (f32), ctx bf16 -> hcat right half
  attn_fused<<<dim3(32, 8), 1024, 0, stream>>>(hcat, encT, encBsh, hcat, out_att);
  // logits = [h,ctx] @ out_W^T + out_b  -> d_out (B,T,C) f32
  gemm_bf16_kernel<<<dim3(250, 32), 256, 0, stream>>>(hcat, outWb, outB, out_logits, 4096, 32000, 1024);
}

// Round 6
// 5020.422 us; speedup vs baseline: 1.0215x; 1.0215x over previous
//
#include <hip/hip_runtime.h>
#include <hip/hip_bf16.h>
#include <stdint.h>

typedef unsigned short u16;
typedef __bf16 bf16x8 __attribute__((ext_vector_type(8)));
typedef float f32x4 __attribute__((ext_vector_type(4)));

// ---------- helpers ----------
__device__ __forceinline__ u16 f2bf(float f) {
  uint32_t u = __float_as_uint(f);
  u = (u + 0x7FFFu + ((u >> 16) & 1u)) >> 16;  // RNE
  return (u16)u;
}
__device__ __forceinline__ float bf2f(u16 x) {
  return __uint_as_float(((uint32_t)x) << 16);
}
__device__ __forceinline__ float blo(uint32_t w) { return __uint_as_float(w << 16); }
__device__ __forceinline__ float bhi(uint32_t w) { return __uint_as_float(w & 0xFFFF0000u); }

__device__ __forceinline__ void gl2lds16(const void* g, void* l) {
  __builtin_amdgcn_global_load_lds(
      (const __attribute__((address_space(1))) void*)g,
      (__attribute__((address_space(3))) void*)l, 16, 0, 0);
}

// ---------- f32 -> bf16 array convert (n4 = count/4, exact) ----------
__global__ void cvt_bf16_arr(const float* __restrict__ in, u16* __restrict__ out, int n4) {
  int i = blockIdx.x * blockDim.x + threadIdx.x;
  if (i >= n4) return;
  float4 v = ((const float4*)in)[i];
  ushort4 o;
  o.x = f2bf(v.x); o.y = f2bf(v.y); o.z = f2bf(v.z); o.w = f2bf(v.w);
  ((ushort4*)out)[i] = o;
}

// ---------- pack Whh[j][k] -> u32 {bf16(k),bf16(k+1)} at [k/2][j] ----------
__global__ void pack_whh(const float* __restrict__ W, uint32_t* __restrict__ out) {
  int idx = blockIdx.x * 256 + threadIdx.x;   // 512 blocks * 256 thr
  int p = idx >> 9, j = idx & 511;
  float a = W[j * 512 + 2 * p];
  float b = W[j * 512 + 2 * p + 1];
  out[p * 512 + j] = (uint32_t)f2bf(a) | ((uint32_t)f2bf(b) << 16);
}

// ---------- gather token embeddings -> bf16 rows (B-major, 128 per batch) ----------
__global__ void gather_embed(const int* __restrict__ tok, const float* __restrict__ embed,
                             u16* __restrict__ out, int tokStride) {
  int m = blockIdx.x;          // 0..4095 : b*128 + pos
  int t = threadIdx.x;         // 128 threads, 4 floats each
  int token = tok[(m >> 7) * tokStride + (m & 127)];
  float4 v = ((const float4*)(embed + (long)token * 512))[t];
  ushort4 o;
  o.x = f2bf(v.x); o.y = f2bf(v.y); o.z = f2bf(v.z); o.w = f2bf(v.w);
  ((ushort4*)(out + (long)m * 512))[t] = o;
}

// ---------- bf16 MFMA GEMM: C[M,N] = A[M,K] * B[N,K]^T (+bias[n]) ----------
// (round-1 verbatim; 128x128 tile, BK=32, 4 waves, 16x16x32 MFMA)
__global__ __launch_bounds__(256) void gemm_bf16_kernel(
    const u16* __restrict__ A, const u16* __restrict__ B,
    const float* __restrict__ bias, float* __restrict__ C,
    int M, int N, int K) {
  __shared__ __align__(16) u16 As[4096];
  __shared__ __align__(16) u16 Bs[4096];
  const int tid = threadIdx.x;
  const int lane = tid & 63;
  const int wv = tid >> 6;
  const int wr = wv >> 1, wc = wv & 1;
  const long m0 = (long)blockIdx.y * 128;
  const long n0 = (long)blockIdx.x * 128;

  f32x4 zero = {0.f, 0.f, 0.f, 0.f};
  f32x4 acc[4][4];
#pragma unroll
  for (int i = 0; i < 4; ++i)
#pragma unroll
    for (int j = 0; j < 4; ++j) acc[i][j] = zero;

  const u16* Ag = A + (m0 + (tid >> 2)) * (long)K + (tid & 3) * 8;
  const u16* Bg = B + (n0 + (tid >> 2)) * (long)K + (tid & 3) * 8;
  const u16* Ag2 = Ag + 64 * (long)K;
  const u16* Bg2 = Bg + 64 * (long)K;
  u16* AsW = As + (tid >> 6) * 512;   // wave-uniform LDS base
  u16* BsW = Bs + (tid >> 6) * 512;
  const int ra = (wr * 64 + (lane & 15)) * 32 + (lane >> 4) * 8;
  const int rb = (wc * 64 + (lane & 15)) * 32 + (lane >> 4) * 8;

  for (int kt = 0; kt < K; kt += 32) {
    __syncthreads();                         // previous-tile reads done
    gl2lds16(Ag + kt, AsW);                  // rows 0..63
    gl2lds16(Ag2 + kt, AsW + 2048);          // rows 64..127
    gl2lds16(Bg + kt, BsW);
    gl2lds16(Bg2 + kt, BsW + 2048);
    __syncthreads();                         // barrier drains vmcnt
    bf16x8 af[4], bfr[4];
#pragma unroll
    for (int i = 0; i < 4; ++i) af[i] = *(const bf16x8*)&As[ra + i * 512];
#pragma unroll
    for (int j = 0; j < 4; ++j) bfr[j] = *(const bf16x8*)&Bs[rb + j * 512];
#pragma unroll
    for (int i = 0; i < 4; ++i)
#pragma unroll
      for (int j = 0; j < 4; ++j)
        acc[i][j] = __builtin_amdgcn_mfma_f32_16x16x32_bf16(af[i], bfr[j], acc[i][j], 0, 0, 0);
  }

#pragma unroll
  for (int i = 0; i < 4; ++i) {
    const long row = m0 + wr * 64 + i * 16 + ((lane >> 4) << 2);
#pragma unroll
    for (int j = 0; j < 4; ++j) {
      const long col = n0 + wc * 64 + j * 16 + (lane & 15);
      const float bv = bias ? bias[col] : 0.f;
#pragma unroll
      for (int r = 0; r < 4; ++r)
        C[(row + r) * (long)N + col] = acc[i][j][r] + bv;
    }
  }
}

// ---------- RNN recurrence: f32 h, register/LDS-resident bf16 weights ----------
// 1 block per batch, 512 threads; thread j owns row Whh[j][:] as 256 bf16-pairs:
// pairs 0..191 in 48 NAMED uint4 VGPR variables, pairs 192..255 in LDS
// (wlds[64][512], 4B lane stride -> conflict-free). h f32 in LDS (broadcast).
// KEY FIX vs rounds 3-5: __launch_bounds__(512, 1) — HIP's 2nd arg behaves as
// CUDA min-blocks/CU; (512,2) capped VGPR at 128 and spilled all weights.
// (512,1) -> 8 waves/CU -> 2 waves/SIMD -> 256-VGPR cap; ~222 needed, no spill.

#define FOR48(M) \
  M(0) M(1) M(2) M(3) M(4) M(5) M(6) M(7) M(8) M(9) M(10) M(11) \
  M(12) M(13) M(14) M(15) M(16) M(17) M(18) M(19) M(20) M(21) M(22) M(23) \
  M(24) M(25) M(26) M(27) M(28) M(29) M(30) M(31) M(32) M(33) M(34) M(35) \
  M(36) M(37) M(38) M(39) M(40) M(41) M(42) M(43) M(44) M(45) M(46) M(47)

__global__ __launch_bounds__(512, 1) void rnn_core(
    const float* __restrict__ pre,            // [B*128][512] f32
    const uint32_t* __restrict__ WhhP,        // [256][512] bf16-pairs [p][j]
    const float* __restrict__ bih, const float* __restrict__ bhh,
    const float* __restrict__ h0,             // [B][512] f32 or null (zeros)
    float* __restrict__ hOutF, long ldF,      // f32 h out (or null)
    u16* __restrict__ hOutB, long ldB_,       // bf16 h out
    float* __restrict__ hLast)                // [B][512] f32 or null
{
  const int b = blockIdx.x, j = threadIdx.x;
  __shared__ __align__(16) float h_sh[512];
  __shared__ uint32_t wlds[64][512];          // pairs 192..255: [p-192][j]
  const uint32_t* Wp = WhhP + j;
  // 192 weight pairs in named uint4 registers (coalesced dword loads)
#define LDW_(i) uint4 wr##i; \
  wr##i.x = Wp[(long)(4*(i)+0) * 512]; wr##i.y = Wp[(long)(4*(i)+1) * 512]; \
  wr##i.z = Wp[(long)(4*(i)+2) * 512]; wr##i.w = Wp[(long)(4*(i)+3) * 512];
  FOR48(LDW_)
#undef LDW_
#pragma unroll
  for (int p = 0; p < 64; ++p) wlds[p][j] = WhhP[(long)(192 + p) * 512 + j];
  const float biasj = bih[j] + bhh[j];
  h_sh[j] = h0 ? h0[(long)b * 512 + j] : 0.f;
  const float* preB = pre + (long)b * 128 * 512 + j;
  __syncthreads();

  for (int t = 0; t < 128; ++t) {
    const float4* H4 = (const float4*)h_sh;
    float a0 = 0.f, a1 = 0.f, a2 = 0.f, a3 = 0.f;
    // pairs 0..191 from named VGPRs
#define ACC_(g) { \
    float4 ha = H4[2*(g)]; \
    float4 hb = H4[2*(g)+1]; \
    a0 += ha.x * blo(wr##g.x) + ha.y * bhi(wr##g.x); \
    a1 += ha.z * blo(wr##g.y) + ha.w * bhi(wr##g.y); \
    a2 += hb.x * blo(wr##g.z) + hb.y * bhi(wr##g.z); \
    a3 += hb.z * blo(wr##g.w) + hb.w * bhi(wr##g.w); }
    FOR48(ACC_)
#undef ACC_
    // pairs 192..255 from LDS
#pragma unroll
    for (int g = 0; g < 16; ++g) {
      float4 ha = H4[96 + 2 * g];
      float4 hb = H4[96 + 2 * g + 1];
      uint32_t w0 = wlds[4 * g][j], w1 = wlds[4 * g + 1][j];
      uint32_t w2 = wlds[4 * g + 2][j], w3 = wlds[4 * g + 3][j];
      a0 += ha.x * blo(w0) + ha.y * bhi(w0);
      a1 += ha.z * blo(w1) + ha.w * bhi(w1);
      a2 += hb.x * blo(w2) + hb.y * bhi(w2);
      a3 += hb.z * blo(w3) + hb.w * bhi(w3);
    }
    float h = tanhf(preB[(long)t * 512] + biasj + ((a0 + a1) + (a2 + a3)));
    __syncthreads();                          // all h_sh reads done
    h_sh[j] = h;
    if (hOutF) hOutF[((long)b * 128 + t) * ldF + j] = h;
    hOutB[((long)b * 128 + t) * ldB_ + j] = f2bf(h);
    if (hLast && t == 127) hLast[(long)b * 512 + j] = h;
    __syncthreads();                          // new h visible
  }
}

// ---------- fused attention: scores -> softmax -> att out -> ctx (all f32) ----------
// grid (32 b, 8 t-groups), block 1024 (16 waves, wave w owns t = y*16+w)
__global__ __launch_bounds__(1024) void attn_fused(
    const u16* __restrict__ hcat,        // bf16, dec_h in cols 0..511
    const float* __restrict__ encT,      // [B][128 s][512] f32
    const float* __restrict__ encBsh,    // [B][128 s][512] f32
    u16* __restrict__ hcatW,             // write ctx into cols 512..1023 (bf16)
    float* __restrict__ attOut)          // [B][128 s][128 t] f32
{
  const int b = blockIdx.x;
  const int w = threadIdx.x >> 6, lane = threadIdx.x & 63;
  const int t = blockIdx.y * 16 + w;
  __shared__ float at[16][128];

  // dec_h row t -> registers (bf16 -> f32)
  float hreg[8];
  const u16* hrow = hcat + ((long)b * 128 + t) * 1024;
#pragma unroll
  for (int i = 0; i < 8; ++i) hreg[i] = bf2f(hrow[lane + i * 64]);

  // scores: score[s] = dec_h[t] . enc_t[s]
  const float* et = encT + (long)b * 128 * 512;
  for (int s = 0; s < 128; ++s) {
    const float* row = et + (long)s * 512;
    float a = 0.f;
#pragma unroll
    for (int i = 0; i < 8; ++i) a += hreg[i] * row[lane + i * 64];
#pragma unroll
    for (int o = 32; o; o >>= 1) a += __shfl_xor(a, o, 64);
    if (lane == 0) at[w][s] = a;
  }
  __syncthreads();

  // softmax over s (per wave, 2 values per lane)
  float s0 = at[w][lane], s1 = at[w][lane + 64];
  float mx = fmaxf(s0, s1);
#pragma unroll
  for (int o = 32; o; o >>= 1) mx = fmaxf(mx, __shfl_xor(mx, o, 64));
  float e0 = __expf(s0 - mx), e1 = __expf(s1 - mx);
  float sm = e0 + e1;
#pragma unroll
  for (int o = 32; o; o >>= 1) sm += __shfl_xor(sm, o, 64);
  float inv = 1.f / sm;
  e0 *= inv; e1 *= inv;
  at[w][lane] = e0;
  at[w][lane + 64] = e1;
  __syncthreads();

  // att output: att[b][s][t]
  attOut[(long)b * 16384 + (long)lane * 128 + t] = e0;
  attOut[(long)b * 16384 + (long)(lane + 64) * 128 + t] = e1;

  // ctx[t][:] = sum_s attn[s] * enc_bsh[s][:]
  float acc[8] = {0.f, 0.f, 0.f, 0.f, 0.f, 0.f, 0.f, 0.f};
  const float* eb = encBsh + (long)b * 128 * 512;
  for (int s = 0; s < 128; ++s) {
    float ws = at[w][s];
    const float* row = eb + (long)s * 512;
#pragma unroll
    for (int i = 0; i < 8; ++i) acc[i] += ws * row[lane + i * 64];
  }
  u16* crow = hcatW + ((long)b * 128 + t) * 1024 + 512;
#pragma unroll
  for (int i = 0; i < 8; ++i) crow[lane + i * 64] = f2bf(acc[i]);
}

// ---------- launcher ----------
extern "C" void kernel_launch(void* const* d_in, const int* in_sizes, int n_in,
                              void* d_out, int out_size, void* d_ws, size_t ws_size,
                              hipStream_t stream) {
  (void)in_sizes; (void)n_in; (void)out_size; (void)ws_size;
  const int*   source = (const int*)d_in[0];
  const int*   target = (const int*)d_in[1];
  const float* embed  = (const float*)d_in[2];
  const float* encWih = (const float*)d_in[3];
  const float* encWhh = (const float*)d_in[4];
  const float* encBih = (const float*)d_in[5];
  const float* encBhh = (const float*)d_in[6];
  const float* decWih = (const float*)d_in[7];
  const float* decWhh = (const float*)d_in[8];
  const float* decBih = (const float*)d_in[9];
  const float* decBhh = (const float*)d_in[10];
  const float* attnW  = (const float*)d_in[11];
  const float* attnB  = (const float*)d_in[12];
  const float* outW   = (const float*)d_in[13];
  const float* outB   = (const float*)d_in[14];

  float* out_logits = (float*)d_out;
  float* out_att = out_logits + (long)32 * 128 * 32000;

  char* wsb = (char*)d_ws;
  size_t off = 0;
  auto alloc = [&](size_t bytes) {
    char* p = wsb + off;
    off += (bytes + 255) & ~(size_t)255;
    return p;
  };
  u16*      encA   = (u16*)alloc(4096l * 512 * 2);
  u16*      decA   = (u16*)alloc(4096l * 512 * 2);
  u16*      wihE   = (u16*)alloc(512l * 512 * 2);
  u16*      wihD   = (u16*)alloc(512l * 512 * 2);
  u16*      attnWb = (u16*)alloc(512l * 512 * 2);
  uint32_t* whhPe  = (uint32_t*)alloc(256l * 512 * 4);
  uint32_t* whhPd  = (uint32_t*)alloc(256l * 512 * 4);
  u16*      outWb  = (u16*)alloc(32000l * 1024 * 2);
  float*    preE   = (float*)alloc(4096l * 512 * 4);
  float*    preD   = (float*)alloc(4096l * 512 * 4);
  float*    encBsh = (float*)alloc(4096l * 512 * 4);
  u16*      encBf  = (u16*)alloc(4096l * 512 * 2);
  float*    encT   = (float*)alloc(4096l * 512 * 4);
  float*    hlast  = (float*)alloc(32l * 512 * 4);
  u16*      hcat   = (u16*)alloc(4096l * 1024 * 2);

  // weight conversions (independent)
  cvt_bf16_arr<<<256, 256, 0, stream>>>(encWih, wihE, 65536);
  cvt_bf16_arr<<<256, 256, 0, stream>>>(decWih, wihD, 65536);
  cvt_bf16_arr<<<256, 256, 0, stream>>>(attnW, attnWb, 65536);
  cvt_bf16_arr<<<32000, 256, 0, stream>>>(outW, outWb, 8192000);
  pack_whh<<<512, 256, 0, stream>>>(encWhh, whhPe);
  pack_whh<<<512, 256, 0, stream>>>(decWhh, whhPd);
  // embedding gathers
  gather_embed<<<4096, 128, 0, stream>>>(source, embed, encA, 128);
  gather_embed<<<4096, 128, 0, stream>>>(target, embed, decA, 129);
  // pre-activations for all timesteps: x @ Wih^T (f32 out)
  gemm_bf16_kernel<<<dim3(4, 32), 256, 0, stream>>>(encA, wihE, (const float*)nullptr, preE, 4096, 512, 512);
  gemm_bf16_kernel<<<dim3(4, 32), 256, 0, stream>>>(decA, wihD, (const float*)nullptr, preD, 4096, 512, 512);
  // encoder recurrence (h0=0): writes enc_bsh f32, encBf bf16, hlast f32
  rnn_core<<<32, 512, 0, stream>>>(preE, whhPe, encBih, encBhh,
      (const float*)nullptr, encBsh, 512, encBf, 512, hlast);
  // enc_t = enc_h @ attn_W^T + attn_b (f32 out)
  gemm_bf16_kernel<<<dim3(4, 32), 256, 0, stream>>>(encBf, attnWb, attnB, encT, 4096, 512, 512);
  // decoder recurrence (h0 = enc last): writes dec_h bf16 into hcat left half
  rnn_core<<<32, 512, 0, stream>>>(preD, whhPd, decBih, decBhh,
      hlast, (float*)nullptr, 512, hcat, 1024, (float*)nullptr);
  // fused attention: scores->softmax->att out->ctx (f32), ctx bf16 -> hcat right half
  attn_fused<<<dim3(32, 8), 1024, 0, stream>>>(hcat, encT, encBsh, hcat, out_att);
  // logits = [h,ctx] @ out_W^T + out_b  -> d_out (B,T,C) f32
  gemm_bf16_kernel<<<dim3(250, 32), 256, 0, stream>>>(hcat, outWb, outB, out_logits, 4096, 32000, 1024);
}

// Round 7
// 5019.678 us; speedup vs baseline: 1.0217x; 1.0001x over previous
//
#include <hip/hip_runtime.h>
#include <hip/hip_bf16.h>
#include <stdint.h>

typedef unsigned short u16;
typedef __bf16 bf16x8 __attribute__((ext_vector_type(8)));
typedef float f32x4 __attribute__((ext_vector_type(4)));

// ---------- helpers ----------
__device__ __forceinline__ u16 f2bf(float f) {
  uint32_t u = __float_as_uint(f);
  u = (u + 0x7FFFu + ((u >> 16) & 1u)) >> 16;  // RNE
  return (u16)u;
}
__device__ __forceinline__ float bf2f(u16 x) {
  return __uint_as_float(((uint32_t)x) << 16);
}
__device__ __forceinline__ float blo(uint32_t w) { return __uint_as_float(w << 16); }
__device__ __forceinline__ float bhi(uint32_t w) { return __uint_as_float(w & 0xFFFF0000u); }

__device__ __forceinline__ void gl2lds16(const void* g, void* l) {
  __builtin_amdgcn_global_load_lds(
      (const __attribute__((address_space(1))) void*)g,
      (__attribute__((address_space(3))) void*)l, 16, 0, 0);
}

// ---------- f32 -> bf16 array convert (n4 = count/4, exact) ----------
__global__ void cvt_bf16_arr(const float* __restrict__ in, u16* __restrict__ out, int n4) {
  int i = blockIdx.x * blockDim.x + threadIdx.x;
  if (i >= n4) return;
  float4 v = ((const float4*)in)[i];
  ushort4 o;
  o.x = f2bf(v.x); o.y = f2bf(v.y); o.z = f2bf(v.z); o.w = f2bf(v.w);
  ((ushort4*)out)[i] = o;
}

// ---------- pack Whh[j][k] -> u32 {bf16(k),bf16(k+1)} at [k/2][j] ----------
__global__ void pack_whh(const float* __restrict__ W, uint32_t* __restrict__ out) {
  int idx = blockIdx.x * 256 + threadIdx.x;   // 512 blocks * 256 thr
  int p = idx >> 9, j = idx & 511;
  float a = W[j * 512 + 2 * p];
  float b = W[j * 512 + 2 * p + 1];
  out[p * 512 + j] = (uint32_t)f2bf(a) | ((uint32_t)f2bf(b) << 16);
}

// ---------- gather token embeddings -> bf16 rows (B-major, 128 per batch) ----------
__global__ void gather_embed(const int* __restrict__ tok, const float* __restrict__ embed,
                             u16* __restrict__ out, int tokStride) {
  int m = blockIdx.x;          // 0..4095 : b*128 + pos
  int t = threadIdx.x;         // 128 threads, 4 floats each
  int token = tok[(m >> 7) * tokStride + (m & 127)];
  float4 v = ((const float4*)(embed + (long)token * 512))[t];
  ushort4 o;
  o.x = f2bf(v.x); o.y = f2bf(v.y); o.z = f2bf(v.z); o.w = f2bf(v.w);
  ((ushort4*)(out + (long)m * 512))[t] = o;
}

// ---------- bf16 MFMA GEMM: C[M,N] = A[M,K] * B[N,K]^T (+bias[n]) ----------
// (round-1 verbatim; 128x128 tile, BK=32, 4 waves, 16x16x32 MFMA)
__global__ __launch_bounds__(256) void gemm_bf16_kernel(
    const u16* __restrict__ A, const u16* __restrict__ B,
    const float* __restrict__ bias, float* __restrict__ C,
    int M, int N, int K) {
  __shared__ __align__(16) u16 As[4096];
  __shared__ __align__(16) u16 Bs[4096];
  const int tid = threadIdx.x;
  const int lane = tid & 63;
  const int wv = tid >> 6;
  const int wr = wv >> 1, wc = wv & 1;
  const long m0 = (long)blockIdx.y * 128;
  const long n0 = (long)blockIdx.x * 128;

  f32x4 zero = {0.f, 0.f, 0.f, 0.f};
  f32x4 acc[4][4];
#pragma unroll
  for (int i = 0; i < 4; ++i)
#pragma unroll
    for (int j = 0; j < 4; ++j) acc[i][j] = zero;

  const u16* Ag = A + (m0 + (tid >> 2)) * (long)K + (tid & 3) * 8;
  const u16* Bg = B + (n0 + (tid >> 2)) * (long)K + (tid & 3) * 8;
  const u16* Ag2 = Ag + 64 * (long)K;
  const u16* Bg2 = Bg + 64 * (long)K;
  u16* AsW = As + (tid >> 6) * 512;   // wave-uniform LDS base
  u16* BsW = Bs + (tid >> 6) * 512;
  const int ra = (wr * 64 + (lane & 15)) * 32 + (lane >> 4) * 8;
  const int rb = (wc * 64 + (lane & 15)) * 32 + (lane >> 4) * 8;

  for (int kt = 0; kt < K; kt += 32) {
    __syncthreads();                         // previous-tile reads done
    gl2lds16(Ag + kt, AsW);                  // rows 0..63
    gl2lds16(Ag2 + kt, AsW + 2048);          // rows 64..127
    gl2lds16(Bg + kt, BsW);
    gl2lds16(Bg2 + kt, BsW + 2048);
    __syncthreads();                         // barrier drains vmcnt
    bf16x8 af[4], bfr[4];
#pragma unroll
    for (int i = 0; i < 4; ++i) af[i] = *(const bf16x8*)&As[ra + i * 512];
#pragma unroll
    for (int j = 0; j < 4; ++j) bfr[j] = *(const bf16x8*)&Bs[rb + j * 512];
#pragma unroll
    for (int i = 0; i < 4; ++i)
#pragma unroll
      for (int j = 0; j < 4; ++j)
        acc[i][j] = __builtin_amdgcn_mfma_f32_16x16x32_bf16(af[i], bfr[j], acc[i][j], 0, 0, 0);
  }

#pragma unroll
  for (int i = 0; i < 4; ++i) {
    const long row = m0 + wr * 64 + i * 16 + ((lane >> 4) << 2);
#pragma unroll
    for (int j = 0; j < 4; ++j) {
      const long col = n0 + wc * 64 + j * 16 + (lane & 15);
      const float bv = bias ? bias[col] : 0.f;
#pragma unroll
      for (int r = 0; r < 4; ++r)
        C[(row + r) * (long)N + col] = acc[i][j][r] + bv;
    }
  }
}

// ---------- RNN recurrence: f32 h, register/LDS-resident bf16 weights ----------
// 1 block per batch, 512 threads; thread j owns row Whh[j][:] as 256 bf16-pairs:
// pairs 0..191 in 48 NAMED uint4 VGPR variables, pairs 192..255 in LDS
// (wlds[64][512], 4B lane stride -> conflict-free). h f32 in LDS (broadcast).
// KEY FIX vs rounds 3-6: SINGLE-ARG __launch_bounds__(512). Any 2-arg form
// makes hipcc emit a >=4-waves/EU constraint -> hard 128-VGPR cap -> the 192
// weight regs spill to scratch (observed: (512,2)->128, (1024,4)->64,
// (512,1)->128, all with ~13MB scratch WRITE). Single-arg leaves the
// allocator free (cf. m97: 164 VGPRs with __launch_bounds__(256)); LDS=130KB
// already limits to 1 block/CU, so ~220 VGPRs cost no occupancy.

#define FOR48(M) \
  M(0) M(1) M(2) M(3) M(4) M(5) M(6) M(7) M(8) M(9) M(10) M(11) \
  M(12) M(13) M(14) M(15) M(16) M(17) M(18) M(19) M(20) M(21) M(22) M(23) \
  M(24) M(25) M(26) M(27) M(28) M(29) M(30) M(31) M(32) M(33) M(34) M(35) \
  M(36) M(37) M(38) M(39) M(40) M(41) M(42) M(43) M(44) M(45) M(46) M(47)

__global__ __launch_bounds__(512) void rnn_core(
    const float* __restrict__ pre,            // [B*128][512] f32
    const uint32_t* __restrict__ WhhP,        // [256][512] bf16-pairs [p][j]
    const float* __restrict__ bih, const float* __restrict__ bhh,
    const float* __restrict__ h0,             // [B][512] f32 or null (zeros)
    float* __restrict__ hOutF, long ldF,      // f32 h out (or null)
    u16* __restrict__ hOutB, long ldB_,       // bf16 h out
    float* __restrict__ hLast)                // [B][512] f32 or null
{
  const int b = blockIdx.x, j = threadIdx.x;
  __shared__ __align__(16) float h_sh[512];
  __shared__ uint32_t wlds[64][512];          // pairs 192..255: [p-192][j]
  const uint32_t* Wp = WhhP + j;
  // 192 weight pairs in named uint4 registers (coalesced dword loads)
#define LDW_(i) uint4 wr##i; \
  wr##i.x = Wp[(long)(4*(i)+0) * 512]; wr##i.y = Wp[(long)(4*(i)+1) * 512]; \
  wr##i.z = Wp[(long)(4*(i)+2) * 512]; wr##i.w = Wp[(long)(4*(i)+3) * 512];
  FOR48(LDW_)
#undef LDW_
#pragma unroll
  for (int p = 0; p < 64; ++p) wlds[p][j] = WhhP[(long)(192 + p) * 512 + j];
  const float biasj = bih[j] + bhh[j];
  h_sh[j] = h0 ? h0[(long)b * 512 + j] : 0.f;
  const float* preB = pre + (long)b * 128 * 512 + j;
  __syncthreads();

  for (int t = 0; t < 128; ++t) {
    const float4* H4 = (const float4*)h_sh;
    float a0 = 0.f, a1 = 0.f, a2 = 0.f, a3 = 0.f;
    // pairs 0..191 from named VGPRs
#define ACC_(g) { \
    float4 ha = H4[2*(g)]; \
    float4 hb = H4[2*(g)+1]; \
    a0 += ha.x * blo(wr##g.x) + ha.y * bhi(wr##g.x); \
    a1 += ha.z * blo(wr##g.y) + ha.w * bhi(wr##g.y); \
    a2 += hb.x * blo(wr##g.z) + hb.y * bhi(wr##g.z); \
    a3 += hb.z * blo(wr##g.w) + hb.w * bhi(wr##g.w); }
    FOR48(ACC_)
#undef ACC_
    // pairs 192..255 from LDS
#pragma unroll
    for (int g = 0; g < 16; ++g) {
      float4 ha = H4[96 + 2 * g];
      float4 hb = H4[96 + 2 * g + 1];
      uint32_t w0 = wlds[4 * g][j], w1 = wlds[4 * g + 1][j];
      uint32_t w2 = wlds[4 * g + 2][j], w3 = wlds[4 * g + 3][j];
      a0 += ha.x * blo(w0) + ha.y * bhi(w0);
      a1 += ha.z * blo(w1) + ha.w * bhi(w1);
      a2 += hb.x * blo(w2) + hb.y * bhi(w2);
      a3 += hb.z * blo(w3) + hb.w * bhi(w3);
    }
    float h = tanhf(preB[(long)t * 512] + biasj + ((a0 + a1) + (a2 + a3)));
    __syncthreads();                          // all h_sh reads done
    h_sh[j] = h;
    if (hOutF) hOutF[((long)b * 128 + t) * ldF + j] = h;
    hOutB[((long)b * 128 + t) * ldB_ + j] = f2bf(h);
    if (hLast && t == 127) hLast[(long)b * 512 + j] = h;
    __syncthreads();                          // new h visible
  }
}

// ---------- fused attention: scores -> softmax -> att out -> ctx (all f32) ----------
// grid (32 b, 8 t-groups), block 1024 (16 waves, wave w owns t = y*16+w)
__global__ __launch_bounds__(1024) void attn_fused(
    const u16* __restrict__ hcat,        // bf16, dec_h in cols 0..511
    const float* __restrict__ encT,      // [B][128 s][512] f32
    const float* __restrict__ encBsh,    // [B][128 s][512] f32
    u16* __restrict__ hcatW,             // write ctx into cols 512..1023 (bf16)
    float* __restrict__ attOut)          // [B][128 s][128 t] f32
{
  const int b = blockIdx.x;
  const int w = threadIdx.x >> 6, lane = threadIdx.x & 63;
  const int t = blockIdx.y * 16 + w;
  __shared__ float at[16][128];

  // dec_h row t -> registers (bf16 -> f32)
  float hreg[8];
  const u16* hrow = hcat + ((long)b * 128 + t) * 1024;
#pragma unroll
  for (int i = 0; i < 8; ++i) hreg[i] = bf2f(hrow[lane + i * 64]);

  // scores: score[s] = dec_h[t] . enc_t[s]
  const float* et = encT + (long)b * 128 * 512;
  for (int s = 0; s < 128; ++s) {
    const float* row = et + (long)s * 512;
    float a = 0.f;
#pragma unroll
    for (int i = 0; i < 8; ++i) a += hreg[i] * row[lane + i * 64];
#pragma unroll
    for (int o = 32; o; o >>= 1) a += __shfl_xor(a, o, 64);
    if (lane == 0) at[w][s] = a;
  }
  __syncthreads();

  // softmax over s (per wave, 2 values per lane)
  float s0 = at[w][lane], s1 = at[w][lane + 64];
  float mx = fmaxf(s0, s1);
#pragma unroll
  for (int o = 32; o; o >>= 1) mx = fmaxf(mx, __shfl_xor(mx, o, 64));
  float e0 = __expf(s0 - mx), e1 = __expf(s1 - mx);
  float sm = e0 + e1;
#pragma unroll
  for (int o = 32; o; o >>= 1) sm += __shfl_xor(sm, o, 64);
  float inv = 1.f / sm;
  e0 *= inv; e1 *= inv;
  at[w][lane] = e0;
  at[w][lane + 64] = e1;
  __syncthreads();

  // att output: att[b][s][t]
  attOut[(long)b * 16384 + (long)lane * 128 + t] = e0;
  attOut[(long)b * 16384 + (long)(lane + 64) * 128 + t] = e1;

  // ctx[t][:] = sum_s attn[s] * enc_bsh[s][:]
  float acc[8] = {0.f, 0.f, 0.f, 0.f, 0.f, 0.f, 0.f, 0.f};
  const float* eb = encBsh + (long)b * 128 * 512;
  for (int s = 0; s < 128; ++s) {
    float ws = at[w][s];
    const float* row = eb + (long)s * 512;
#pragma unroll
    for (int i = 0; i < 8; ++i) acc[i] += ws * row[lane + i * 64];
  }
  u16* crow = hcatW + ((long)b * 128 + t) * 1024 + 512;
#pragma unroll
  for (int i = 0; i < 8; ++i) crow[lane + i * 64] = f2bf(acc[i]);
}

// ---------- launcher ----------
extern "C" void kernel_launch(void* const* d_in, const int* in_sizes, int n_in,
                              void* d_out, int out_size, void* d_ws, size_t ws_size,
                              hipStream_t stream) {
  (void)in_sizes; (void)n_in; (void)out_size; (void)ws_size;
  const int*   source = (const int*)d_in[0];
  const int*   target = (const int*)d_in[1];
  const float* embed  = (const float*)d_in[2];
  const float* encWih = (const float*)d_in[3];
  const float* encWhh = (const float*)d_in[4];
  const float* encBih = (const float*)d_in[5];
  const float* encBhh = (const float*)d_in[6];
  const float* decWih = (const float*)d_in[7];
  const float* decWhh = (const float*)d_in[8];
  const float* decBih = (const float*)d_in[9];
  const float* decBhh = (const float*)d_in[10];
  const float* attnW  = (const float*)d_in[11];
  const float* attnB  = (const float*)d_in[12];
  const float* outW   = (const float*)d_in[13];
  const float* outB   = (const float*)d_in[14];

  float* out_logits = (float*)d_out;
  float* out_att = out_logits + (long)32 * 128 * 32000;

  char* wsb = (char*)d_ws;
  size_t off = 0;
  auto alloc = [&](size_t bytes) {
    char* p = wsb + off;
    off += (bytes + 255) & ~(size_t)255;
    return p;
  };
  u16*      encA   = (u16*)alloc(4096l * 512 * 2);
  u16*      decA   = (u16*)alloc(4096l * 512 * 2);
  u16*      wihE   = (u16*)alloc(512l * 512 * 2);
  u16*      wihD   = (u16*)alloc(512l * 512 * 2);
  u16*      attnWb = (u16*)alloc(512l * 512 * 2);
  uint32_t* whhPe  = (uint32_t*)alloc(256l * 512 * 4);
  uint32_t* whhPd  = (uint32_t*)alloc(256l * 512 * 4);
  u16*      outWb  = (u16*)alloc(32000l * 1024 * 2);
  float*    preE   = (float*)alloc(4096l * 512 * 4);
  float*    preD   = (float*)alloc(4096l * 512 * 4);
  float*    encBsh = (float*)alloc(4096l * 512 * 4);
  u16*      encBf  = (u16*)alloc(4096l * 512 * 2);
  float*    encT   = (float*)alloc(4096l * 512 * 4);
  float*    hlast  = (float*)alloc(32l * 512 * 4);
  u16*      hcat   = (u16*)alloc(4096l * 1024 * 2);

  // weight conversions (independent)
  cvt_bf16_arr<<<256, 256, 0, stream>>>(encWih, wihE, 65536);
  cvt_bf16_arr<<<256, 256, 0, stream>>>(decWih, wihD, 65536);
  cvt_bf16_arr<<<256, 256, 0, stream>>>(attnW, attnWb, 65536);
  cvt_bf16_arr<<<32000, 256, 0, stream>>>(outW, outWb, 8192000);
  pack_whh<<<512, 256, 0, stream>>>(encWhh, whhPe);
  pack_whh<<<512, 256, 0, stream>>>(decWhh, whhPd);
  // embedding gathers
  gather_embed<<<4096, 128, 0, stream>>>(source, embed, encA, 128);
  gather_embed<<<4096, 128, 0, stream>>>(target, embed, decA, 129);
  // pre-activations for all timesteps: x @ Wih^T (f32 out)
  gemm_bf16_kernel<<<dim3(4, 32), 256, 0, stream>>>(encA, wihE, (const float*)nullptr, preE, 4096, 512, 512);
  gemm_bf16_kernel<<<dim3(4, 32), 256, 0, stream>>>(decA, wihD, (const float*)nullptr, preD, 4096, 512, 512);
  // encoder recurrence (h0=0): writes enc_bsh f32, encBf bf16, hlast f32
  rnn_core<<<32, 512, 0, stream>>>(preE, whhPe, encBih, encBhh,
      (const float*)nullptr, encBsh, 512, encBf, 512, hlast);
  // enc_t = enc_h @ attn_W^T + attn_b (f32 out)
  gemm_bf16_kernel<<<dim3(4, 32), 256, 0, stream>>>(encBf, attnWb, attnB, encT, 4096, 512, 512);
  // decoder recurrence (h0 = enc last): writes dec_h bf16 into hcat left half
  rnn_core<<<32, 512, 0, stream>>>(preD, whhPd, decBih, decBhh,
      hlast, (float*)nullptr, 512, hcat, 1024, (float*)nullptr);
  // fused attention: scores->softmax->att out->ctx (f32), ctx bf16 -> hcat right half
  attn_fused<<<dim3(32, 8), 1024, 0, stream>>>(hcat, encT, encBsh, hcat, out_att);
  // logits = [h,ctx] @ out_W^T + out_b  -> d_out (B,T,C) f32
  gemm_bf16_kernel<<<dim3(250, 32), 256, 0, stream>>>(hcat, outWb, outB, out_logits, 4096, 32000, 1024);
}